// Round 2
// baseline (290.668 us; speedup 1.0000x reference)
//
#include <hip/hip_runtime.h>
#include <hip/hip_cooperative_groups.h>
#include <math.h>

namespace cg = cooperative_groups;

#define NQ 19
#define NL 3
#define NSTATE (1 << NQ)
#define TPB 256
#define CHUNK 2048      // amplitudes per block tile (16 KB LDS)
#define NBLK 256        // one block per CU; all co-resident
#define PI_F 3.14159265358979323846f

__device__ __forceinline__ float2 cmul(float2 a, float2 b) {
    return make_float2(a.x * b.x - a.y * b.y, a.x * b.y + a.y * b.x);
}
__device__ __forceinline__ float2 cadd(float2 a, float2 b) {
    return make_float2(a.x + b.x, a.y + b.y);
}

// Fused U = RZ(tz) * RY(ty) * RX(tx) for qubit q at layer l.
__device__ void make_U(const float* inputs, const float* yw, const float* zw,
                       int l, int q, bool useRZ, float2* U) {
    float x = inputs[q];
    float ax;
    if (q >= NQ - 2) {
        ax = (x >= 0.5f) ? PI_F : 0.0f;          // directional: snap {0, pi}
    } else {
        ax = (x + 1.5f) * (2.0f * PI_F / 3.0f);  // [-1.5,1.5] -> [0,2pi]
        ax = fminf(fmaxf(ax, 0.0f), 2.0f * PI_F);
    }
    float ty = yw[l * NQ + q];
    float tz = useRZ ? zw[l * NQ + q] : 0.0f;
    float cx = cosf(0.5f * ax), sx = sinf(0.5f * ax);
    float cy = cosf(0.5f * ty), sy = sinf(0.5f * ty);
    float cz = cosf(0.5f * tz), sz = sinf(0.5f * tz);
    float2 m00 = make_float2(cy * cx, sy * sx);
    float2 m01 = make_float2(-sy * cx, -cy * sx);
    float2 m10 = make_float2(sy * cx, -cy * sx);
    float2 m11 = make_float2(cy * cx, -sy * sx);
    float2 e0 = make_float2(cz, -sz);
    float2 e1 = make_float2(cz, sz);
    U[0] = cmul(e0, m00);
    U[1] = cmul(e0, m01);
    U[2] = cmul(e1, m10);
    U[3] = cmul(e1, m11);
}

// Single cooperative kernel: 3 layers x (passA: bits 0..10 local; passB: bits
// 11..18 + 0..2 local), CZ-ring sign fused into passB store, final layer's
// passB computes expval partials and atomicAdds into out.
__global__ __launch_bounds__(TPB) void qsim(const float* __restrict__ inputs,
                                            const float* __restrict__ yw,
                                            const float* __restrict__ zw,
                                            float2* __restrict__ state,
                                            float* __restrict__ out) {
    cg::grid_group grid = cg::this_grid();
    __shared__ float2 amp[CHUNK];
    __shared__ float2 U[11][4];
    __shared__ float red[32];
    const int t = threadIdx.x;
    const int c = blockIdx.x;

    // Zero out[] for the atomic accumulation; all adds happen after >=5 grid
    // syncs, so this store is safely ordered before them.
    if (c == 0 && t < 8) out[t] = 0.0f;

    for (int layer = 0; layer < NL; ++layer) {
        // ---------------- pass A: bits 0..10 local (contiguous chunk) --------
        if (t < 11) {
            int p = t;              // bit position
            int q = NQ - 1 - p;     // qubit (bit 18 == qubit 0)
            make_U(inputs, yw, zw, layer, q, (layer != NL - 1), &U[p][0]);
        }
        if (layer == 0) {
            for (int i = t; i < CHUNK; i += TPB) amp[i] = make_float2(0.f, 0.f);
            if (c == 0 && t == 0) amp[0] = make_float2(1.f, 0.f);
        } else {
            const float2* g = state + (size_t)c * CHUNK;
            for (int i = t; i < CHUNK; i += TPB) amp[i] = g[i];
        }
        __syncthreads();

        for (int b = 0; b < 11; ++b) {
            const float2 u00 = U[b][0], u01 = U[b][1], u10 = U[b][2], u11 = U[b][3];
            for (int pp = t; pp < CHUNK / 2; pp += TPB) {
                int i0 = ((pp >> b) << (b + 1)) | (pp & ((1 << b) - 1));
                int i1 = i0 | (1 << b);
                float2 a0 = amp[i0], a1 = amp[i1];
                amp[i0] = cadd(cmul(u00, a0), cmul(u01, a1));
                amp[i1] = cadd(cmul(u10, a0), cmul(u11, a1));
            }
            __syncthreads();
        }
        {
            float2* g = state + (size_t)c * CHUNK;
            for (int i = t; i < CHUNK; i += TPB) g[i] = amp[i];
        }
        grid.sync();

        // ---------------- pass B: bits 11..18 + 0..2 local -------------------
        if (t < 8) {
            int p = 11 + t;
            int q = NQ - 1 - p;     // qubits 7..0
            make_U(inputs, yw, zw, layer, q, (layer != NL - 1), &U[t][0]);
        }
        // local li = h*8 + lo  ->  global x = (h<<11) | (c<<3) | lo
        for (int li = t; li < CHUNK; li += TPB) {
            int h = li >> 3, lo = li & 7;
            int x = (h << 11) | (c << 3) | lo;
            amp[li] = state[x];
        }
        __syncthreads();

        for (int j = 0; j < 8; ++j) {
            const int b = 3 + j;    // local bit == global bit 11+j
            const float2 u00 = U[j][0], u01 = U[j][1], u10 = U[j][2], u11 = U[j][3];
            for (int pp = t; pp < CHUNK / 2; pp += TPB) {
                int i0 = ((pp >> b) << (b + 1)) | (pp & ((1 << b) - 1));
                int i1 = i0 | (1 << b);
                float2 a0 = amp[i0], a1 = amp[i1];
                amp[i0] = cadd(cmul(u00, a0), cmul(u01, a1));
                amp[i1] = cadd(cmul(u10, a0), cmul(u11, a1));
            }
            __syncthreads();
        }

        if (layer < NL - 1) {
            // CZ ring diagonal sign: parity of adjacent-bit pairs + wrap(18,0)
            for (int li = t; li < CHUNK; li += TPB) {
                int h = li >> 3, lo = li & 7;
                int x = (h << 11) | (c << 3) | lo;
                unsigned adj = ((unsigned)x & ((unsigned)x >> 1)) & 0x3FFFFu;
                int par = (__popc(adj) + ((x & 1) & ((x >> 18) & 1))) & 1;
                float s = par ? -1.0f : 1.0f;
                float2 a = amp[li];
                state[x] = make_float2(s * a.x, s * a.y);
            }
            grid.sync();
        } else {
            // Final layer: probs + expvals. Measured qubits 0..7 = bits 7..0 of h.
            float ps[8];
#pragma unroll
            for (int w = 0; w < 8; ++w) ps[w] = 0.0f;
            for (int li = t; li < CHUNK; li += TPB) {
                float2 a = amp[li];
                float p = a.x * a.x + a.y * a.y;
                int h = li >> 3;
#pragma unroll
                for (int w = 0; w < 8; ++w) ps[w] += ((h >> (7 - w)) & 1) ? -p : p;
            }
            const int lane = t & 63, wid = t >> 6;
#pragma unroll
            for (int w = 0; w < 8; ++w) {
                float v = ps[w];
                for (int off = 32; off; off >>= 1) v += __shfl_down(v, off, 64);
                if (lane == 0) red[wid * 8 + w] = v;
            }
            __syncthreads();
            if (t < 8) {
                float v = red[0 * 8 + t] + red[1 * 8 + t] +
                          red[2 * 8 + t] + red[3 * 8 + t];
                atomicAdd(&out[t], v);   // device-scope by default
            }
        }
    }
}

extern "C" void kernel_launch(void* const* d_in, const int* in_sizes, int n_in,
                              void* d_out, int out_size, void* d_ws, size_t ws_size,
                              hipStream_t stream) {
    const float* inputs = (const float*)d_in[0];   // [19]
    const float* yw     = (const float*)d_in[1];   // [3,19]
    const float* zw     = (const float*)d_in[2];   // [3,19]
    float* out = (float*)d_out;                    // [8] float32
    float2* state = (float2*)d_ws;                 // 4 MB scratch

    void* args[] = { (void*)&inputs, (void*)&yw, (void*)&zw,
                     (void*)&state, (void*)&out };
    hipLaunchCooperativeKernel((void*)qsim, dim3(NBLK), dim3(TPB),
                               args, 0, stream);
}

// Round 3
// 93.398 us; speedup vs baseline: 3.1121x; 3.1121x over previous
//
#include <hip/hip_runtime.h>
#include <math.h>

#define NQ 19
#define NSTATE (1 << NQ)
#define TPB 256
#define CHUNK 2048      // amplitudes per block tile (16 KB LDS)
#define NBLK 256
#define PI_F 3.14159265358979323846f

__device__ __forceinline__ float2 cmul(float2 a, float2 b) {
    return make_float2(a.x * b.x - a.y * b.y, a.x * b.y + a.y * b.x);
}
__device__ __forceinline__ float2 cadd(float2 a, float2 b) {
    return make_float2(a.x + b.x, a.y + b.y);
}

// Fused U = RZ(tz) * RY(ty) * RX(ax) for qubit q at layer l (0-based).
__device__ void make_U(const float* inputs, const float* yw, const float* zw,
                       int l, int q, bool useRZ, float2* U) {
    float x = inputs[q];
    float ax;
    if (q >= NQ - 2) {
        ax = (x >= 0.5f) ? PI_F : 0.0f;          // directional: snap {0, pi}
    } else {
        ax = (x + 1.5f) * (2.0f * PI_F / 3.0f);  // [-1.5,1.5] -> [0,2pi]
        ax = fminf(fmaxf(ax, 0.0f), 2.0f * PI_F);
    }
    float ty = yw[l * NQ + q];
    float tz = useRZ ? zw[l * NQ + q] : 0.0f;
    float cx = cosf(0.5f * ax), sx = sinf(0.5f * ax);
    float cy = cosf(0.5f * ty), sy = sinf(0.5f * ty);
    float cz = cosf(0.5f * tz), sz = sinf(0.5f * tz);
    float2 m00 = make_float2(cy * cx, sy * sx);
    float2 m01 = make_float2(-sy * cx, -cy * sx);
    float2 m10 = make_float2(sy * cx, -cy * sx);
    float2 m11 = make_float2(cy * cx, -sy * sx);
    float2 e0 = make_float2(cz, -sz);
    float2 e1 = make_float2(cz, sz);
    U[0] = cmul(e0, m00);
    U[1] = cmul(e0, m01);
    U[2] = cmul(e1, m10);
    U[3] = cmul(e1, m11);
}

// CZ-ring diagonal sign parity for global index x: adjacent bit pairs
// (b,b+1) b=0..17 plus the wrap pair (bits 18,0).
__device__ __forceinline__ int cz_parity(int x) {
    unsigned adj = ((unsigned)x & ((unsigned)x >> 1)) & 0x3FFFFu;
    return (__popc(adj) + ((x & 1) & ((x >> 18) & 1))) & 1;
}

// P1: generate analytic post-(L1 + CZ1) product state per element, then apply
// L2 gates on bits 0..10 (contiguous chunks). Also zeroes out[].
__global__ __launch_bounds__(TPB) void pass1(const float* __restrict__ inputs,
                                             const float* __restrict__ yw,
                                             const float* __restrict__ zw,
                                             float2* __restrict__ state,
                                             float* __restrict__ out) {
    __shared__ float2 amp[CHUNK];
    __shared__ float2 U[11][4];
    __shared__ float2 col0[19][2];   // L1 gate column 0 per bit position
    const int t = threadIdx.x;
    const int c = blockIdx.x;        // global bits 11..18

    if (c == 0 && t < 8) out[t] = 0.0f;

    if (t < 19) {
        float2 u[4];
        make_U(inputs, yw, zw, 0, NQ - 1 - t, true, u);  // bit t <-> qubit 18-t
        col0[t][0] = u[0];           // u00
        col0[t][1] = u[2];           // u10
    }
    if (t >= 64 && t < 64 + 11) {    // separate wave computes L2A gates
        int b = t - 64;
        make_U(inputs, yw, zw, 1, NQ - 1 - b, true, &U[b][0]);
    }
    __syncthreads();

    // Per-block prefactor: bits 11..18 from c.
    float2 ph = make_float2(1.f, 0.f);
#pragma unroll
    for (int b = 11; b < 19; ++b) ph = cmul(ph, col0[b][(c >> (b - 11)) & 1]);
    // Per-thread: bits 0..7 from t.
    float2 base = ph;
#pragma unroll
    for (int b = 0; b < 8; ++b) base = cmul(base, col0[b][(t >> b) & 1]);
    // Elements li = k*256 + t; bits 8..10 from k. Apply CZ1 sign per element.
#pragma unroll
    for (int k = 0; k < 8; ++k) {
        float2 v = base;
#pragma unroll
        for (int b = 8; b < 11; ++b) v = cmul(v, col0[b][(k >> (b - 8)) & 1]);
        int li = (k << 8) | t;
        int x = (c << 11) | li;
        float s = cz_parity(x) ? -1.0f : 1.0f;
        amp[li] = make_float2(s * v.x, s * v.y);
    }
    __syncthreads();

    for (int b = 0; b < 11; ++b) {
        const float2 u00 = U[b][0], u01 = U[b][1], u10 = U[b][2], u11 = U[b][3];
        for (int pp = t; pp < CHUNK / 2; pp += TPB) {
            int i0 = ((pp >> b) << (b + 1)) | (pp & ((1 << b) - 1));
            int i1 = i0 | (1 << b);
            float2 a0 = amp[i0], a1 = amp[i1];
            amp[i0] = cadd(cmul(u00, a0), cmul(u01, a1));
            amp[i1] = cadd(cmul(u10, a0), cmul(u11, a1));
        }
        __syncthreads();
    }

    float2* g = state + (size_t)c * CHUNK;
    for (int i = t; i < CHUNK; i += TPB) g[i] = amp[i];
}

// P2: strided tile (bits 11..18 + 0..2 local; bits 3..10 = blockIdx).
// Apply L2 gates on bits 11..18, CZ2 sign, L3 RX*RY gates on bits 11..18.
__global__ __launch_bounds__(TPB) void pass2(const float* __restrict__ inputs,
                                             const float* __restrict__ yw,
                                             const float* __restrict__ zw,
                                             float2* __restrict__ state) {
    __shared__ float2 amp[CHUNK];
    __shared__ float2 U2[8][4];
    __shared__ float2 U3[8][4];
    const int t = threadIdx.x;
    const int T = blockIdx.x;        // global bits 3..10

    if (t < 8) {
        make_U(inputs, yw, zw, 1, NQ - 1 - (11 + t), true, &U2[t][0]);
    } else if (t >= 64 && t < 72) {
        int j = t - 64;
        make_U(inputs, yw, zw, 2, NQ - 1 - (11 + j), false, &U3[j][0]);
    }

    // li = h*8 + lo -> x = (h<<11) | (T<<3) | lo
    for (int li = t; li < CHUNK; li += TPB) {
        int h = li >> 3, lo = li & 7;
        amp[li] = state[(h << 11) | (T << 3) | lo];
    }
    __syncthreads();

    for (int j = 0; j < 8; ++j) {
        const int b = 3 + j;
        const float2 u00 = U2[j][0], u01 = U2[j][1], u10 = U2[j][2], u11 = U2[j][3];
        for (int pp = t; pp < CHUNK / 2; pp += TPB) {
            int i0 = ((pp >> b) << (b + 1)) | (pp & ((1 << b) - 1));
            int i1 = i0 | (1 << b);
            float2 a0 = amp[i0], a1 = amp[i1];
            amp[i0] = cadd(cmul(u00, a0), cmul(u01, a1));
            amp[i1] = cadd(cmul(u10, a0), cmul(u11, a1));
        }
        __syncthreads();
    }

    // CZ2 sign in LDS.
    for (int li = t; li < CHUNK; li += TPB) {
        int h = li >> 3, lo = li & 7;
        int x = (h << 11) | (T << 3) | lo;
        float s = cz_parity(x) ? -1.0f : 1.0f;
        float2 a = amp[li];
        amp[li] = make_float2(s * a.x, s * a.y);
    }
    __syncthreads();

    for (int j = 0; j < 8; ++j) {
        const int b = 3 + j;
        const float2 u00 = U3[j][0], u01 = U3[j][1], u10 = U3[j][2], u11 = U3[j][3];
        for (int pp = t; pp < CHUNK / 2; pp += TPB) {
            int i0 = ((pp >> b) << (b + 1)) | (pp & ((1 << b) - 1));
            int i1 = i0 | (1 << b);
            float2 a0 = amp[i0], a1 = amp[i1];
            amp[i0] = cadd(cmul(u00, a0), cmul(u01, a1));
            amp[i1] = cadd(cmul(u10, a0), cmul(u11, a1));
        }
        __syncthreads();
    }

    for (int li = t; li < CHUNK; li += TPB) {
        int h = li >> 3, lo = li & 7;
        state[(h << 11) | (T << 3) | lo] = amp[li];
    }
}

// P3: contiguous chunks; L3 RX*RY on bits 0..10, then block prob sum.
// Measured qubits 0..7 = global bits 18..11 = bits 7..0 of blockIdx, so each
// block contributes +/- its total probability to each expval.
__global__ __launch_bounds__(TPB) void pass3(const float* __restrict__ inputs,
                                             const float* __restrict__ yw,
                                             const float* __restrict__ zw,
                                             const float2* __restrict__ state,
                                             float* __restrict__ out) {
    __shared__ float2 amp[CHUNK];
    __shared__ float2 U[11][4];
    __shared__ float red[4];
    const int t = threadIdx.x;
    const int c = blockIdx.x;

    if (t < 11) {
        make_U(inputs, yw, zw, 2, NQ - 1 - t, false, &U[t][0]);
    }
    const float2* g = state + (size_t)c * CHUNK;
    for (int i = t; i < CHUNK; i += TPB) amp[i] = g[i];
    __syncthreads();

    for (int b = 0; b < 11; ++b) {
        const float2 u00 = U[b][0], u01 = U[b][1], u10 = U[b][2], u11 = U[b][3];
        for (int pp = t; pp < CHUNK / 2; pp += TPB) {
            int i0 = ((pp >> b) << (b + 1)) | (pp & ((1 << b) - 1));
            int i1 = i0 | (1 << b);
            float2 a0 = amp[i0], a1 = amp[i1];
            amp[i0] = cadd(cmul(u00, a0), cmul(u01, a1));
            amp[i1] = cadd(cmul(u10, a0), cmul(u11, a1));
        }
        __syncthreads();
    }

    float p = 0.0f;
    for (int i = t; i < CHUNK; i += TPB) {
        float2 a = amp[i];
        p += a.x * a.x + a.y * a.y;
    }
    const int lane = t & 63, wid = t >> 6;
    for (int off = 32; off; off >>= 1) p += __shfl_down(p, off, 64);
    if (lane == 0) red[wid] = p;
    __syncthreads();
    if (t < 8) {
        float total = red[0] + red[1] + red[2] + red[3];
        float s = ((c >> (7 - t)) & 1) ? -total : total;
        atomicAdd(&out[t], s);
    }
}

extern "C" void kernel_launch(void* const* d_in, const int* in_sizes, int n_in,
                              void* d_out, int out_size, void* d_ws, size_t ws_size,
                              hipStream_t stream) {
    const float* inputs = (const float*)d_in[0];   // [19]
    const float* yw     = (const float*)d_in[1];   // [3,19]
    const float* zw     = (const float*)d_in[2];   // [3,19]
    float* out = (float*)d_out;                    // [8] float32
    float2* state = (float2*)d_ws;                 // 4 MB scratch

    pass1<<<NBLK, TPB, 0, stream>>>(inputs, yw, zw, state, out);
    pass2<<<NBLK, TPB, 0, stream>>>(inputs, yw, zw, state);
    pass3<<<NBLK, TPB, 0, stream>>>(inputs, yw, zw, state, out);
}

// Round 4
// 84.414 us; speedup vs baseline: 3.4434x; 1.1064x over previous
//
#include <hip/hip_runtime.h>
#include <math.h>

#define NQ 19
#define NSTATE (1 << NQ)
#define TPB 256
#define CHUNK 2048      // amplitudes per block tile (16 KB LDS)
#define NBLK 256
#define PI_F 3.14159265358979323846f

__device__ __forceinline__ float2 cmul(float2 a, float2 b) {
    return make_float2(a.x * b.x - a.y * b.y, a.x * b.y + a.y * b.x);
}
__device__ __forceinline__ float2 cadd(float2 a, float2 b) {
    return make_float2(a.x + b.x, a.y + b.y);
}

__device__ __forceinline__ float enc_angle(float x, int q) {
    if (q >= NQ - 2) return (x >= 0.5f) ? PI_F : 0.0f;   // directional
    float ax = (x + 1.5f) * (2.0f * PI_F / 3.0f);        // [-1.5,1.5]->[0,2pi]
    return fminf(fmaxf(ax, 0.0f), 2.0f * PI_F);
}

// Fused U = RZ(tz) * RY(ty) * RX(ax) for qubit q at layer l (0-based).
__device__ void make_U(const float* inputs, const float* yw, const float* zw,
                       int l, int q, bool useRZ, float2* U) {
    float ax = enc_angle(inputs[q], q);
    float ty = yw[l * NQ + q];
    float tz = useRZ ? zw[l * NQ + q] : 0.0f;
    float cx = cosf(0.5f * ax), sx = sinf(0.5f * ax);
    float cy = cosf(0.5f * ty), sy = sinf(0.5f * ty);
    float cz = cosf(0.5f * tz), sz = sinf(0.5f * tz);
    float2 m00 = make_float2(cy * cx, sy * sx);
    float2 m01 = make_float2(-sy * cx, -cy * sx);
    float2 m10 = make_float2(sy * cx, -cy * sx);
    float2 m11 = make_float2(cy * cx, -sy * sx);
    float2 e0 = make_float2(cz, -sz);
    float2 e1 = make_float2(cz, sz);
    U[0] = cmul(e0, m00);
    U[1] = cmul(e0, m01);
    U[2] = cmul(e1, m10);
    U[3] = cmul(e1, m11);
}

// CZ-ring diagonal sign parity: adjacent bit pairs (b,b+1) b=0..17 + wrap (18,0).
__device__ __forceinline__ int cz_parity(int x) {
    unsigned adj = ((unsigned)x & ((unsigned)x >> 1)) & 0x3FFFFu;
    return (__popc(adj) + ((x & 1) & ((x >> 18) & 1))) & 1;
}

// P1: analytic post-(L1 + CZ1) product state per element, then L2 gates on
// bits 0..10 (contiguous chunks). Also zeroes out[].
__global__ __launch_bounds__(TPB) void pass1(const float* __restrict__ inputs,
                                             const float* __restrict__ yw,
                                             const float* __restrict__ zw,
                                             float2* __restrict__ state,
                                             float* __restrict__ out) {
    __shared__ __align__(16) float2 amp[CHUNK];
    __shared__ float2 U[11][4];
    __shared__ float2 col0[19][2];   // L1 gate column 0 per bit position
    const int t = threadIdx.x;
    const int c = blockIdx.x;        // global bits 11..18

    if (c == 0 && t < 8) out[t] = 0.0f;

    if (t < 19) {
        float2 u[4];
        make_U(inputs, yw, zw, 0, NQ - 1 - t, true, u);  // bit t <-> qubit 18-t
        col0[t][0] = u[0];           // u00
        col0[t][1] = u[2];           // u10
    }
    if (t >= 64 && t < 64 + 11) {    // separate wave computes L2 low-bit gates
        int b = t - 64;
        make_U(inputs, yw, zw, 1, NQ - 1 - b, true, &U[b][0]);
    }
    __syncthreads();

    // Per-block prefactor: bits 11..18 from c.
    float2 ph = make_float2(1.f, 0.f);
#pragma unroll
    for (int b = 11; b < 19; ++b) ph = cmul(ph, col0[b][(c >> (b - 11)) & 1]);
    // Per-thread: bits 0..7 from t.
    float2 base = ph;
#pragma unroll
    for (int b = 0; b < 8; ++b) base = cmul(base, col0[b][(t >> b) & 1]);
    // Elements li = k*256 + t; bits 8..10 from k; CZ1 sign per element.
#pragma unroll
    for (int k = 0; k < 8; ++k) {
        float2 v = base;
#pragma unroll
        for (int b = 8; b < 11; ++b) v = cmul(v, col0[b][(k >> (b - 8)) & 1]);
        int li = (k << 8) | t;
        int x = (c << 11) | li;
        float s = cz_parity(x) ? -1.0f : 1.0f;
        amp[li] = make_float2(s * v.x, s * v.y);
    }
    __syncthreads();

    for (int b = 0; b < 11; ++b) {
        const float2 u00 = U[b][0], u01 = U[b][1], u10 = U[b][2], u11 = U[b][3];
        for (int pp = t; pp < CHUNK / 2; pp += TPB) {
            int i0 = ((pp >> b) << (b + 1)) | (pp & ((1 << b) - 1));
            int i1 = i0 | (1 << b);
            float2 a0 = amp[i0], a1 = amp[i1];
            amp[i0] = cadd(cmul(u00, a0), cmul(u01, a1));
            amp[i1] = cadd(cmul(u10, a0), cmul(u11, a1));
        }
        __syncthreads();
    }

    float4* g4 = (float4*)(state + (size_t)c * CHUNK);
    const float4* a4 = (const float4*)amp;
    for (int i = t; i < CHUNK / 2; i += TPB) g4[i] = a4[i];
}

// P2: strided tile (bits 11..18 + 0..2 local; bits 3..10 = blockIdx).
// L2 gates on bits 11..18, then per-measured-qubit reduced-density-matrix
// accumulation with CZ2's relative sign folded in; expvals via the analytic
// <Z> = cx*cy*(p0-p1) - 2*sy*Re(rho01) - 2*sx*cy*Im(rho01) formula (V=RY*RX).
// L3 gates on unmeasured qubits and all diagonal layer-3 ops provably cancel.
__global__ __launch_bounds__(TPB) void pass2(const float* __restrict__ inputs,
                                             const float* __restrict__ yw,
                                             const float* __restrict__ zw,
                                             const float2* __restrict__ state,
                                             float* __restrict__ out) {
    __shared__ __align__(16) float2 amp[CHUNK];
    __shared__ float2 U2[8][4];
    __shared__ float red[4][32];
    const int t = threadIdx.x;
    const int T = blockIdx.x;        // global bits 3..10

    if (t < 8) {
        make_U(inputs, yw, zw, 1, NQ - 1 - (11 + t), true, &U2[t][0]);
    }

    // Vectorized strided load: thread m covers li = 2m, 2m+1.
    // li = h*8+lo -> x = (h<<11)|(T<<3)|lo ; consecutive lo pair = 16B.
    {
        const float4* s4 = (const float4*)state;
        float4* a4 = (float4*)amp;
        for (int m = t; m < CHUNK / 2; m += TPB) {
            int h = m >> 2, lo2 = (m & 3) << 1;          // lo = lo2, lo2+1
            int x = (h << 11) | (T << 3) | lo2;
            a4[m] = s4[x >> 1];
        }
    }
    __syncthreads();

    // L2 sweeps on local bits 3..10 (global 11..18).
    for (int j = 0; j < 8; ++j) {
        const int b = 3 + j;
        const float2 u00 = U2[j][0], u01 = U2[j][1], u10 = U2[j][2], u11 = U2[j][3];
        for (int pp = t; pp < CHUNK / 2; pp += TPB) {
            int i0 = ((pp >> b) << (b + 1)) | (pp & ((1 << b) - 1));
            int i1 = i0 | (1 << b);
            float2 a0 = amp[i0], a1 = amp[i1];
            amp[i0] = cadd(cmul(u00, a0), cmul(u01, a1));
            amp[i1] = cadd(cmul(u10, a0), cmul(u11, a1));
        }
        __syncthreads();
    }

    // Per measured bit j (local bit 3+j, global bit 11+j, qubit 7-j):
    // p0, p1, rho01 = sum s_rel * a0*conj(a1), where s_rel is CZ2's relative
    // sign between x and x^(1<<(11+j)): parity of bits {10+j,12+j} (j<7) or
    // {17,0} (j==7) of x.
    float acc[8][4];
#pragma unroll
    for (int j = 0; j < 8; ++j)
#pragma unroll
        for (int k = 0; k < 4; ++k) acc[j][k] = 0.0f;

#pragma unroll
    for (int j = 0; j < 8; ++j) {
        const int b = 3 + j;
        const unsigned mask = (j < 7) ? ((1u << (10 + j)) | (1u << (12 + j)))
                                      : ((1u << 17) | 1u);
#pragma unroll
        for (int it = 0; it < (CHUNK / 2) / TPB; ++it) {
            int pp = it * TPB + t;
            int i0 = ((pp >> b) << (b + 1)) | (pp & ((1 << b) - 1));
            int i1 = i0 | (1 << b);
            float2 a0 = amp[i0], a1 = amp[i1];
            int x0 = ((i0 >> 3) << 11) | (T << 3) | (i0 & 7);
            float s = (__popc((unsigned)x0 & mask) & 1) ? -1.0f : 1.0f;
            acc[j][0] += a0.x * a0.x + a0.y * a0.y;
            acc[j][1] += a1.x * a1.x + a1.y * a1.y;
            acc[j][2] += s * (a0.x * a1.x + a0.y * a1.y);   // Re(a0*conj(a1))
            acc[j][3] += s * (a0.y * a1.x - a0.x * a1.y);   // Im(a0*conj(a1))
        }
    }

    const int lane = t & 63, wid = t >> 6;
#pragma unroll
    for (int j = 0; j < 8; ++j)
#pragma unroll
        for (int k = 0; k < 4; ++k) {
            float v = acc[j][k];
            for (int off = 32; off; off >>= 1) v += __shfl_down(v, off, 64);
            if (lane == 0) red[wid][j * 4 + k] = v;
        }
    __syncthreads();

    if (t < 8) {
        const int j = t, q = 7 - j;          // qubit index
        float p0 = red[0][j*4+0] + red[1][j*4+0] + red[2][j*4+0] + red[3][j*4+0];
        float p1 = red[0][j*4+1] + red[1][j*4+1] + red[2][j*4+1] + red[3][j*4+1];
        float cr = red[0][j*4+2] + red[1][j*4+2] + red[2][j*4+2] + red[3][j*4+2];
        float ci = red[0][j*4+3] + red[1][j*4+3] + red[2][j*4+3] + red[3][j*4+3];
        float ax = enc_angle(inputs[q], q);
        float ty = yw[2 * NQ + q];
        float z = cosf(ax) * cosf(ty) * (p0 - p1)
                - 2.0f * sinf(ty) * cr
                - 2.0f * sinf(ax) * cosf(ty) * ci;
        atomicAdd(&out[q], z);
    }
}

extern "C" void kernel_launch(void* const* d_in, const int* in_sizes, int n_in,
                              void* d_out, int out_size, void* d_ws, size_t ws_size,
                              hipStream_t stream) {
    const float* inputs = (const float*)d_in[0];   // [19]
    const float* yw     = (const float*)d_in[1];   // [3,19]
    const float* zw     = (const float*)d_in[2];   // [3,19]
    float* out = (float*)d_out;                    // [8] float32
    float2* state = (float2*)d_ws;                 // 4 MB scratch

    pass1<<<NBLK, TPB, 0, stream>>>(inputs, yw, zw, state, out);
    pass2<<<NBLK, TPB, 0, stream>>>(inputs, yw, zw, state, out);
}

// Round 5
// 71.481 us; speedup vs baseline: 4.0663x; 1.1809x over previous
//
#include <hip/hip_runtime.h>
#include <math.h>

#define NQ 19
#define PI_F 3.14159265358979323846f

// ---------- complex 2x2 matrix algebra ----------
struct c2 { float2 a00, a01, a10, a11; };

__device__ __forceinline__ float2 cmulc(float2 p, float2 q) {
    return make_float2(p.x * q.x - p.y * q.y, p.x * q.y + p.y * q.x);
}
__device__ __forceinline__ float2 caddc(float2 p, float2 q) {
    return make_float2(p.x + q.x, p.y + q.y);
}
__device__ __forceinline__ float2 cconj(float2 p) { return make_float2(p.x, -p.y); }

__device__ c2 mmul(const c2& A, const c2& B) {
    c2 r;
    r.a00 = caddc(cmulc(A.a00, B.a00), cmulc(A.a01, B.a10));
    r.a01 = caddc(cmulc(A.a00, B.a01), cmulc(A.a01, B.a11));
    r.a10 = caddc(cmulc(A.a10, B.a00), cmulc(A.a11, B.a10));
    r.a11 = caddc(cmulc(A.a10, B.a01), cmulc(A.a11, B.a11));
    return r;
}
__device__ c2 mdag(const c2& A) {
    c2 r;
    r.a00 = cconj(A.a00); r.a01 = cconj(A.a10);
    r.a10 = cconj(A.a01); r.a11 = cconj(A.a11);
    return r;
}
__device__ c2 conjby(const c2& F, const c2& u) {   // u† F u
    return mmul(mdag(u), mmul(F, u));
}
__device__ __forceinline__ c2 mat_I() {
    c2 r; r.a00 = make_float2(1.f, 0.f); r.a01 = make_float2(0.f, 0.f);
    r.a10 = make_float2(0.f, 0.f); r.a11 = make_float2(1.f, 0.f); return r;
}
__device__ __forceinline__ c2 mat_Z() {
    c2 r; r.a00 = make_float2(1.f, 0.f); r.a01 = make_float2(0.f, 0.f);
    r.a10 = make_float2(0.f, 0.f); r.a11 = make_float2(-1.f, 0.f); return r;
}

__device__ __forceinline__ float enc_angle(float x, int q) {
    if (q >= NQ - 2) return (x >= 0.5f) ? PI_F : 0.0f;   // directional snap
    float ax = (x + 1.5f) * (2.0f * PI_F / 3.0f);        // [-1.5,1.5]->[0,2pi]
    return fminf(fmaxf(ax, 0.0f), 2.0f * PI_F);
}

// Per-qubit layer gate u = RZ(tz) * RY(ty) * RX(ax)  (matrix of last-applied first)
__device__ c2 gate_u(const float* inputs, const float* yw, const float* zw,
                     int l, int q) {
    float ax = enc_angle(inputs[q], q);
    float ty = yw[l * NQ + q];
    float tz = zw[l * NQ + q];
    float cx = cosf(0.5f * ax), sx = sinf(0.5f * ax);
    float cy = cosf(0.5f * ty), sy = sinf(0.5f * ty);
    float cz = cosf(0.5f * tz), sz = sinf(0.5f * tz);
    c2 RX; RX.a00 = make_float2(cx, 0.f); RX.a01 = make_float2(0.f, -sx);
           RX.a10 = make_float2(0.f, -sx); RX.a11 = make_float2(cx, 0.f);
    c2 RY; RY.a00 = make_float2(cy, 0.f); RY.a01 = make_float2(-sy, 0.f);
           RY.a10 = make_float2(sy, 0.f); RY.a11 = make_float2(cy, 0.f);
    c2 RZ; RZ.a00 = make_float2(cz, -sz); RZ.a01 = make_float2(0.f, 0.f);
           RZ.a10 = make_float2(0.f, 0.f); RZ.a11 = make_float2(cz, sz);
    return mmul(RZ, mmul(RY, RX));
}

// Apply one CZ1-split factor choice to the 5-slot array.
// p: slot index 1..3 (rel position -1,0,+1). off=false: diag part of F;
// off=true: offdiag part of F on slot p, Z multiplied onto slots p-1, p+1.
__device__ void apply_factor(c2* slot, bool* used, int p, const c2& F, bool off) {
    c2 part = F;
    if (!off) { part.a01 = make_float2(0.f, 0.f); part.a10 = make_float2(0.f, 0.f); }
    else      { part.a00 = make_float2(0.f, 0.f); part.a11 = make_float2(0.f, 0.f); }
    slot[p] = mmul(slot[p], part); used[p] = true;
    if (off) {
        c2 Zm = mat_Z();
        slot[p - 1] = mmul(slot[p - 1], Zm); used[p - 1] = true;
        slot[p + 1] = mmul(slot[p + 1], Zm); used[p + 1] = true;
    }
}

// Evaluate <0| term |0>: conjugate each used slot by u0(q), take [0][0], multiply.
__device__ float2 eval_term(const c2* slot, const bool* used, const c2* u0) {
    float2 val = make_float2(1.f, 0.f);
#pragma unroll
    for (int p = 0; p < 5; ++p) {
        if (used[p]) {
            c2 G = conjby(slot[p], u0[p]);
            val = cmulc(val, G.a00);
        }
    }
    return val;
}

// Heisenberg-picture closed form: lane w computes <Z_w> for the full
// 3-layer circuit. Observable support never exceeds ring-qubits {w-2..w+2}.
__global__ __launch_bounds__(64) void heis(const float* __restrict__ inputs,
                                           const float* __restrict__ yw,
                                           const float* __restrict__ zw,
                                           float* __restrict__ out) {
    const int w = threadIdx.x;
    if (w >= 8) return;

    // Support qubits, rel positions -2..+2 on the CZ ring (cycle mod 19).
    int qs[5];
#pragma unroll
    for (int p = 0; p < 5; ++p) qs[p] = (w + p - 2 + NQ) % NQ;

    const c2 Zm = mat_Z();

    // L3: A = u3(w)† Z u3(w)   (CZ3 and layer-3 RZ commute with Z_w)
    c2 A = conjby(Zm, gate_u(inputs, yw, zw, 2, w));
    c2 Ad = A; Ad.a01 = make_float2(0.f, 0.f); Ad.a10 = make_float2(0.f, 0.f);
    c2 Ao = A; Ao.a00 = make_float2(0.f, 0.f); Ao.a11 = make_float2(0.f, 0.f);

    // CZ2: Ad stays on w; Ao picks up Z on w-1, w+1. Then conj by U2 per qubit.
    c2 u2w = gate_u(inputs, yw, zw, 1, w);
    c2 B  = conjby(Ad, u2w);                                  // term T1 factor
    c2 C  = conjby(Ao, u2w);                                  // T2, rel 0
    c2 Dm = conjby(Zm, gate_u(inputs, yw, zw, 1, qs[1]));     // T2, rel -1
    c2 Dp = conjby(Zm, gate_u(inputs, yw, zw, 1, qs[3]));     // T2, rel +1

    // L1 gates for all 5 support qubits.
    c2 u0[5];
#pragma unroll
    for (int p = 0; p < 5; ++p) u0[p] = gate_u(inputs, yw, zw, 0, qs[p]);

    float2 total = make_float2(0.f, 0.f);

    // T1: single factor B at rel 0; CZ1 split -> 2 terms.
    for (int ch = 0; ch < 2; ++ch) {
        c2 slot[5]; bool used[5];
#pragma unroll
        for (int p = 0; p < 5; ++p) { slot[p] = mat_I(); used[p] = false; }
        apply_factor(slot, used, 2, B, ch & 1);
        total = caddc(total, eval_term(slot, used, u0));
    }

    // T2: factors (rel -1: Dm), (rel 0: C), (rel +1: Dp); CZ1 split -> 8 terms.
    for (int ch = 0; ch < 8; ++ch) {
        c2 slot[5]; bool used[5];
#pragma unroll
        for (int p = 0; p < 5; ++p) { slot[p] = mat_I(); used[p] = false; }
        apply_factor(slot, used, 1, Dm, ch & 1);
        apply_factor(slot, used, 2, C, (ch >> 1) & 1);
        apply_factor(slot, used, 3, Dp, (ch >> 2) & 1);
        total = caddc(total, eval_term(slot, used, u0));
    }

    out[w] = total.x;   // Hermitian observable: imaginary part ~ 0
}

extern "C" void kernel_launch(void* const* d_in, const int* in_sizes, int n_in,
                              void* d_out, int out_size, void* d_ws, size_t ws_size,
                              hipStream_t stream) {
    const float* inputs = (const float*)d_in[0];   // [19]
    const float* yw     = (const float*)d_in[1];   // [3,19]
    const float* zw     = (const float*)d_in[2];   // [3,19]
    float* out = (float*)d_out;                    // [8] float32

    heis<<<1, 64, 0, stream>>>(inputs, yw, zw, out);
}